// Round 16
// baseline (102.849 us; speedup 1.0000x reference)
//
#include <hip/hip_runtime.h>
#include <hip/hip_bf16.h>

// HeteroLinear fused forward on gfx950: out[i] = x[i] @ W[tv[i]] + b[tv[i]]
// N=131072, IN=OUT=256, T=8, tv sorted. HBM floor ~256 MB -> ~41 us.
// R16: R13's proven wave-level code, re-packaged in QUARTER-size blocks so
// multi-block co-residency finally happens:
//  - block = 4 waves (256 thr) = 128 rows x 64 cols; W-slice 32 KB LDS
//  - ~105 VGPR, 32 KB LDS -> 4 blocks/CU co-resident = 16 waves/CU and 4
//    independent barrier domains per CU (stage-drain of one block overlaps
//    compute of three others). All prior 8-wave variants: 8 waves/CU, one
//    domain, pinned at ~88 us profiled (R8/R10/R13/R15).
//  - bijective XCD map: the 4 col-slices of a row-group go to the SAME XCD
//    (x re-reads L2-hit); 4096 % 8 == 0.
//  - everything else verbatim R13: dist-2 raw f32x4 x-prefetch, src-side
//    XOR-swizzled global_load_lds W stage, swizzled ds_read_b128,
//    swapped-operand MFMA, plain f32x4 stores, integer RNE f2bf.

#define NROWS 131072
#define KD 256
#define ND 256
#define BR 128                      // rows per block
#define BC 64                       // cols per block
#define NRG (NROWS / BR)            // 1024 row-groups
#define NCS (ND / BC)               // 4 col-slices
#define NBLK (NRG * NCS)            // 4096

typedef __attribute__((ext_vector_type(8))) short short8;
typedef __attribute__((ext_vector_type(4))) float f32x4;
typedef __attribute__((ext_vector_type(4))) float flt4;

typedef __attribute__((address_space(3))) unsigned int lds_u32_t;
typedef __attribute__((address_space(1))) unsigned int glb_u32_t;

__device__ inline unsigned short f2bf(float f) {
    unsigned int u = __float_as_uint(f);
    u += 0x7FFFu + ((u >> 16) & 1u);   // RNE
    return (unsigned short)(u >> 16);
}

// ---- weight prep: wT[t][n][k] = bf16(w[t][k][n]) ----
__global__ __launch_bounds__(256) void prep_weights(const float* __restrict__ w,
                                                    unsigned short* __restrict__ wT) {
    __shared__ unsigned short L[8][264];
    const int t  = blockIdx.x >> 5;
    const int k0 = (blockIdx.x & 31) * 8;
    const int tid = threadIdx.x;

    #pragma unroll
    for (int i = 0; i < 2; ++i) {
        int idx = i * 256 + tid;
        int kr  = idx >> 6;
        int nq  = idx & 63;
        const flt4* src = (const flt4*)(w + ((size_t)t * 256 + k0 + kr) * 256);
        flt4 v = src[nq];
        #pragma unroll
        for (int j = 0; j < 4; ++j) L[kr][nq * 4 + j] = f2bf(v[j]);
    }
    __syncthreads();

    int n = tid;
    short8 v;
    #pragma unroll
    for (int j = 0; j < 8; ++j) v[j] = (short)L[j][n];
    *(short8*)(wT + ((size_t)t * 256 + n) * 256 + k0) = v;
}

// ---- main GEMM: 4-wave blocks, 32 KB W-slice in LDS ----
__global__ __launch_bounds__(256) void hetero_gemm(
        const float* __restrict__ x, const int* __restrict__ tv,
        const unsigned short* __restrict__ wT, const float* __restrict__ bias,
        float* __restrict__ out) {
    // W[t] col-slice: 64 cols x 256 k bf16, [local col][k], 512 B/col,
    // XOR-swizzled 16B chunks: LDS chunk c of col holds global chunk c^(col&7).
    __shared__ short Bs[BC * KD];            // 32 KiB -> 4+ blocks/CU

    const int tid  = threadIdx.x;
    const int lane = tid & 63;
    const int wv   = tid >> 6;               // 4 waves
    const int cl   = lane & 15;
    const int kg   = lane >> 4;
    // XCD map: physical b -> xcd = b%8 (round-robin). Give each XCD a
    // contiguous run of row-groups; the 4 col-slices of one row-group sit
    // on consecutive same-XCD blocks (b, b+8, b+16, b+24) -> x L2-hits.
    const int wgid = (blockIdx.x & 7) * (NBLK / 8) + (blockIdx.x >> 3);
    const int rg   = wgid >> 2;              // row-group
    const int c0   = (wgid & 3) * BC;        // col-slice base
    const int r0   = rg * BR;
    const int rw   = r0 + wv * 32;           // wave's 32-row strip

    const int tmin = tv[r0];
    const int tmax = tv[r0 + BR - 1];
    const int ty0  = tv[rw + cl];            // type of row (m=0)
    const int ty1  = tv[rw + 16 + cl];       // type of row (m=1)
    const int s    = cl & 7;                 // swizzle key (col&7 == cl&7)

    // per-lane x row pointers (rows rw+m*16+cl), k-offset kg*8
    const float* xr0 = x + (size_t)(rw + cl) * KD + kg * 8;
    const float* xr1 = x + (size_t)(rw + 16 + cl) * KD + kg * 8;

    for (int t = tmin; t <= tmax; ++t) {
        if (t > tmin) __syncthreads();       // prev-pass reads done before overwrite

        // ---- stage W[t][c0..c0+63][*] -> LDS: 2048 16B chunks, 8 rounds ----
        {
            const unsigned short* Wt = wT + (size_t)t * (KD * ND);
            #pragma unroll
            for (int rnd = 0; rnd < 8; ++rnd) {
                int i  = rnd * 256 + tid;    // chunk index 0..2047
                int lc = i >> 5;             // local col 0..63
                int c  = i & 31;
                int sc = c ^ (lc & 7);       // source-side swizzle
                const unsigned short* gp = Wt + (size_t)(c0 + lc) * KD + sc * 8;
                __builtin_amdgcn_global_load_lds(
                    (const glb_u32_t*)gp,
                    (lds_u32_t*)((char*)Bs + (size_t)(rnd * 256 + wv * 64) * 16),
                    16, 0, 0);
            }
        }
        __syncthreads();                     // drain DMA; slice ready

        f32x4 zero = {0.f, 0.f, 0.f, 0.f};
        f32x4 acc[2][4];
        #pragma unroll
        for (int m = 0; m < 2; ++m)
            #pragma unroll
            for (int n = 0; n < 4; ++n) acc[m][n] = zero;

        // dist-2 raw prefetch: two 4x-f32x4 buffers, consume-then-reissue
        f32x4 xbA[4], xbB[4];
        xbA[0] = *(const f32x4*)(xr0);          // ks=0
        xbA[1] = *(const f32x4*)(xr0 + 4);
        xbA[2] = *(const f32x4*)(xr1);
        xbA[3] = *(const f32x4*)(xr1 + 4);
        xbB[0] = *(const f32x4*)(xr0 + 32);     // ks=1
        xbB[1] = *(const f32x4*)(xr0 + 36);
        xbB[2] = *(const f32x4*)(xr1 + 32);
        xbB[3] = *(const f32x4*)(xr1 + 36);

        auto step = [&](f32x4 (&xb)[4], int ks) {
            short8 a[2];
            #pragma unroll
            for (int m = 0; m < 2; ++m) {
                #pragma unroll
                for (int j = 0; j < 4; ++j) {
                    a[m][j]     = (short)f2bf(xb[2 * m][j]);
                    a[m][4 + j] = (short)f2bf(xb[2 * m + 1][j]);
                }
            }
            if (ks + 2 < 8) {                // reissue freed buffer for ks+2
                xb[0] = *(const f32x4*)(xr0 + (ks + 2) * 32);
                xb[1] = *(const f32x4*)(xr0 + (ks + 2) * 32 + 4);
                xb[2] = *(const f32x4*)(xr1 + (ks + 2) * 32);
                xb[3] = *(const f32x4*)(xr1 + (ks + 2) * 32 + 4);
            }
            #pragma unroll
            for (int n = 0; n < 4; ++n) {
                int lc = n * 16 + cl;                 // local col 0..63
                int kc = ((ks << 2) | kg) ^ s;        // swizzled 16B chunk
                short8 b = *(const short8*)((char*)Bs + (size_t)lc * 512 + (kc << 4));
                // swapped operands: D[w-col][x-row]
                acc[0][n] = __builtin_amdgcn_mfma_f32_16x16x32_bf16(b, a[0], acc[0][n], 0, 0, 0);
                acc[1][n] = __builtin_amdgcn_mfma_f32_16x16x32_bf16(b, a[1], acc[1][n], 0, 0, 0);
            }
        };
        step(xbA, 0); step(xbB, 1); step(xbA, 2); step(xbB, 3);
        step(xbA, 4); step(xbB, 5); step(xbA, 6); step(xbB, 7);

        // ---- epilogue: rows rw+m*16+cl, cols c0+n*16+kg*4 (plain stores) ----
        #pragma unroll
        for (int m = 0; m < 2; ++m) {
            int tym = (m == 0) ? ty0 : ty1;
            if (tym == t) {
                float* orow = out + (size_t)(rw + m * 16 + cl) * ND + c0 + kg * 4;
                #pragma unroll
                for (int n = 0; n < 4; ++n) {
                    f32x4 bv = *(const f32x4*)(bias + (size_t)t * ND + c0 + n * 16 + kg * 4);
                    *(f32x4*)(orow + n * 16) = acc[m][n] + bv;
                }
            }
        }
    }
}

extern "C" void kernel_launch(void* const* d_in, const int* in_sizes, int n_in,
                              void* d_out, int out_size, void* d_ws, size_t ws_size,
                              hipStream_t stream) {
    const float* x    = (const float*)d_in[0];
    const int*   tv   = (const int*)d_in[1];
    const float* w    = (const float*)d_in[2];
    const float* bias = (const float*)d_in[3];
    float* out = (float*)d_out;
    unsigned short* wT = (unsigned short*)d_ws;   // 8*256*256*2 = 1 MiB

    prep_weights<<<dim3(256), dim3(256), 0, stream>>>(w, wT);
    hetero_gemm<<<dim3(NBLK), dim3(256), 0, stream>>>(x, tv, wT, bias, out);
}

// Round 17
// 68.104 us; speedup vs baseline: 1.5102x; 1.5102x over previous
//
#include <hip/hip_runtime.h>
#include <hip/hip_bf16.h>

// HeteroLinear fused forward on gfx950: out[i] = x[i] @ W[tv[i]] + b[tv[i]]
// N=131072, IN=OUT=256, T=8, tv sorted. HBM floor ~256 MB -> ~41 us.
// R17 = R13 (best, 66.8 us) with the ONE proven lever extended:
// x-prefetch depth 2 -> 3. Enabled by shrinking acc: wave computes its
// 32 rows x 256 cols in FOUR col-quarters (acc[2][4]=32 VGPR) against the
// same 128 KB LDS W-tile, freeing 48 VGPR for a rotating 3-buffer raw
// f32x4 prefetch (cover ~3 ks-steps >= HBM latency). Quarters 2-4 re-issue
// x loads as L1/L2 hits. Pressure ~115 < 128 cap (WRITE is the tripwire).
// Everything else verbatim R13: src-side XOR-swizzled global_load_lds W
// stage, swizzled ds_read_b128, swapped-operand MFMA, plain f32x4 stores.

#define NROWS 131072
#define KD 256
#define ND 256
#define BM 256                      // rows per block
#define NBLK (NROWS / BM)           // 512

typedef __attribute__((ext_vector_type(8))) short short8;
typedef __attribute__((ext_vector_type(4))) float f32x4;
typedef __attribute__((ext_vector_type(4))) float flt4;

typedef __attribute__((address_space(3))) unsigned int lds_u32_t;
typedef __attribute__((address_space(1))) unsigned int glb_u32_t;

__device__ inline unsigned short f2bf(float f) {
    unsigned int u = __float_as_uint(f);
    u += 0x7FFFu + ((u >> 16) & 1u);   // RNE
    return (unsigned short)(u >> 16);
}

// ---- weight prep: wT[t][n][k] = bf16(w[t][k][n]) ----
__global__ __launch_bounds__(256) void prep_weights(const float* __restrict__ w,
                                                    unsigned short* __restrict__ wT) {
    __shared__ unsigned short L[8][264];
    const int t  = blockIdx.x >> 5;
    const int k0 = (blockIdx.x & 31) * 8;
    const int tid = threadIdx.x;

    #pragma unroll
    for (int i = 0; i < 2; ++i) {
        int idx = i * 256 + tid;
        int kr  = idx >> 6;
        int nq  = idx & 63;
        const flt4* src = (const flt4*)(w + ((size_t)t * 256 + k0 + kr) * 256);
        flt4 v = src[nq];
        #pragma unroll
        for (int j = 0; j < 4; ++j) L[kr][nq * 4 + j] = f2bf(v[j]);
    }
    __syncthreads();

    int n = tid;
    short8 v;
    #pragma unroll
    for (int j = 0; j < 8; ++j) v[j] = (short)L[j][n];
    *(short8*)(wT + ((size_t)t * 256 + n) * 256 + k0) = v;
}

// ---- main GEMM ----
__global__ __launch_bounds__(512) void hetero_gemm(
        const float* __restrict__ x, const int* __restrict__ tv,
        const unsigned short* __restrict__ wT, const float* __restrict__ bias,
        float* __restrict__ out) {
    // W[t] tile, bf16, [col][k], 512 B per col-row, XOR-swizzled 16B chunks:
    // LDS chunk c of col holds global k-chunk c ^ (col&7).
    __shared__ short Bs[BM * KD];            // 128 KiB

    const int tid  = threadIdx.x;
    const int lane = tid & 63;
    const int wv   = tid >> 6;               // 8 waves
    const int cl   = lane & 15;
    const int kg   = lane >> 4;
    const int r0   = blockIdx.x * BM;
    const int rw   = r0 + wv * 32;           // wave's 32-row strip

    const int tmin = tv[r0];
    const int tmax = tv[r0 + BM - 1];
    const int ty0  = tv[rw + cl];            // type of row (m=0)
    const int ty1  = tv[rw + 16 + cl];       // type of row (m=1)
    const int s    = cl & 7;                 // swizzle key (col&7 == cl&7)

    // per-lane x row pointers (rows rw+m*16+cl), k-offset kg*8
    const float* xr0 = x + (size_t)(rw + cl) * KD + kg * 8;
    const float* xr1 = x + (size_t)(rw + 16 + cl) * KD + kg * 8;

    for (int t = tmin; t <= tmax; ++t) {
        if (t > tmin) __syncthreads();       // prev-pass reads done before overwrite

        // ---- stage W[t] -> LDS: 8192 16B chunks, 16 wave-rounds ----
        {
            const unsigned short* Wt = wT + (size_t)t * (KD * ND);
            #pragma unroll
            for (int rnd = 0; rnd < 16; ++rnd) {
                int i   = rnd * 512 + tid;   // chunk index 0..8191 (per-lane)
                int col = i >> 5;
                int c   = i & 31;
                int sc  = c ^ (col & 7);     // source-side swizzle
                const unsigned short* gp = Wt + col * KD + sc * 8;
                __builtin_amdgcn_global_load_lds(
                    (const glb_u32_t*)gp,
                    (lds_u32_t*)((char*)Bs + (size_t)(rnd * 512 + wv * 64) * 16),
                    16, 0, 0);
            }
        }
        __syncthreads();                     // drain DMA; tile ready

        // ---- compute in four col-quarters: acc 32 VGPR, prefetch 48 ----
        #pragma unroll
        for (int q = 0; q < 4; ++q) {
            const int c0 = q * 64;

            f32x4 zero = {0.f, 0.f, 0.f, 0.f};
            f32x4 acc[2][4];
            #pragma unroll
            for (int m = 0; m < 2; ++m)
                #pragma unroll
                for (int n = 0; n < 4; ++n) acc[m][n] = zero;

            // rotating dist-3 raw prefetch: 3 buffers, consume-then-reissue
            f32x4 xbA[4], xbB[4], xbC[4];
            xbA[0] = *(const f32x4*)(xr0);          // ks=0
            xbA[1] = *(const f32x4*)(xr0 + 4);
            xbA[2] = *(const f32x4*)(xr1);
            xbA[3] = *(const f32x4*)(xr1 + 4);
            xbB[0] = *(const f32x4*)(xr0 + 32);     // ks=1
            xbB[1] = *(const f32x4*)(xr0 + 36);
            xbB[2] = *(const f32x4*)(xr1 + 32);
            xbB[3] = *(const f32x4*)(xr1 + 36);
            xbC[0] = *(const f32x4*)(xr0 + 64);     // ks=2
            xbC[1] = *(const f32x4*)(xr0 + 68);
            xbC[2] = *(const f32x4*)(xr1 + 64);
            xbC[3] = *(const f32x4*)(xr1 + 68);

            auto step = [&](f32x4 (&xb)[4], int ks) {
                short8 a[2];
                #pragma unroll
                for (int m = 0; m < 2; ++m) {
                    #pragma unroll
                    for (int j = 0; j < 4; ++j) {
                        a[m][j]     = (short)f2bf(xb[2 * m][j]);
                        a[m][4 + j] = (short)f2bf(xb[2 * m + 1][j]);
                    }
                }
                if (ks + 3 < 8) {            // reissue freed buffer for ks+3
                    xb[0] = *(const f32x4*)(xr0 + (ks + 3) * 32);
                    xb[1] = *(const f32x4*)(xr0 + (ks + 3) * 32 + 4);
                    xb[2] = *(const f32x4*)(xr1 + (ks + 3) * 32);
                    xb[3] = *(const f32x4*)(xr1 + (ks + 3) * 32 + 4);
                }
                #pragma unroll
                for (int n = 0; n < 4; ++n) {
                    int lc = c0 + n * 16 + cl;            // col
                    int kc = ((ks << 2) | kg) ^ s;        // swizzled 16B chunk
                    short8 b = *(const short8*)((char*)Bs + (size_t)lc * 512 + (kc << 4));
                    // swapped operands: D[w-col][x-row]
                    acc[0][n] = __builtin_amdgcn_mfma_f32_16x16x32_bf16(b, a[0], acc[0][n], 0, 0, 0);
                    acc[1][n] = __builtin_amdgcn_mfma_f32_16x16x32_bf16(b, a[1], acc[1][n], 0, 0, 0);
                }
            };
            step(xbA, 0); step(xbB, 1); step(xbC, 2);
            step(xbA, 3); step(xbB, 4); step(xbC, 5);
            step(xbA, 6); step(xbB, 7);

            // ---- epilogue: rows rw+m*16+cl, cols c0+n*16+kg*4 (plain stores) ----
            #pragma unroll
            for (int m = 0; m < 2; ++m) {
                int tym = (m == 0) ? ty0 : ty1;
                if (tym == t) {
                    float* orow = out + (size_t)(rw + m * 16 + cl) * ND + c0 + kg * 4;
                    #pragma unroll
                    for (int n = 0; n < 4; ++n) {
                        f32x4 bv = *(const f32x4*)(bias + (size_t)t * ND + c0 + n * 16 + kg * 4);
                        *(f32x4*)(orow + n * 16) = acc[m][n] + bv;
                    }
                }
            }
        }
    }
}

extern "C" void kernel_launch(void* const* d_in, const int* in_sizes, int n_in,
                              void* d_out, int out_size, void* d_ws, size_t ws_size,
                              hipStream_t stream) {
    const float* x    = (const float*)d_in[0];
    const int*   tv   = (const int*)d_in[1];
    const float* w    = (const float*)d_in[2];
    const float* bias = (const float*)d_in[3];
    float* out = (float*)d_out;
    unsigned short* wT = (unsigned short*)d_ws;   // 8*256*256*2 = 1 MiB

    prep_weights<<<dim3(256), dim3(256), 0, stream>>>(w, wT);
    hetero_gemm<<<dim3(NBLK), dim3(512), 0, stream>>>(x, tv, wT, bias, out);
}